// Round 3
// baseline (2180.421 us; speedup 1.0000x reference)
//
#include <hip/hip_runtime.h>

#define HID 64
#define TLEN 1024
#define GATES 256  // 4*HID

__device__ __forceinline__ float fast_rcp(float x) { return __builtin_amdgcn_rcpf(x); }

__device__ __forceinline__ float fsig(float x) {
    float e = __expf(-x);
    return fast_rcp(1.0f + e);
}

__device__ __forceinline__ float ftanh(float x) {
    float e = __expf(-2.0f * fabsf(x));
    float t = (1.0f - e) * fast_rcp(1.0f + e);
    return copysignf(t, x);
}

// One workgroup per batch element. 768 threads = 12 waves.
//   tids   0..255 : layer0 gate rows (W_hh0 row r in regs, + W_ih0[r][0..2], fused bias)
//   tids 256..511 : layer1 input rows (W_ih1 row r, fused bias)
//   tids 512..767 : layer1 recurrent rows (W_hh1 row r)
// Software pipeline: phase A of iter t computes layer0 dots for time t AND
// layer1 dots for time t-1 (u1 from a[t-1], v1 from b[t-2]) — all waves busy.
// Phase B: wave0 combines layer0 -> a[t]; wave1 combines layer1 -> b[t-1],
// does the 3-wide output projection (shfl reduce) and writes out[t-1].
__global__ __launch_bounds__(768, 3)
void lstm_fused(const float* __restrict__ x,
                const float* __restrict__ W_ih0, const float* __restrict__ W_hh0,
                const float* __restrict__ b_ih0, const float* __restrict__ b_hh0,
                const float* __restrict__ W_ih1, const float* __restrict__ W_hh1,
                const float* __restrict__ b_ih1, const float* __restrict__ b_hh1,
                const float* __restrict__ W_out, const float* __restrict__ b_out,
                float* __restrict__ out)
{
    __shared__ __align__(16) float a_lds[HID];   // layer0 hidden state
    __shared__ __align__(16) float b_lds[HID];   // layer1 hidden state
    __shared__ __align__(16) float g0[GATES];    // layer0 gate preacts
    __shared__ __align__(16) float u1[GATES];    // W_ih1 @ a
    __shared__ __align__(16) float v1[GATES];    // W_hh1 @ b

    const int tid  = threadIdx.x;
    const int bidx = blockIdx.x;
    const int role = tid >> 8;      // 0,1,2
    const int r    = tid & 255;

    const float* xb = x   + (size_t)bidx * TLEN * 3;
    float*       ob = out + (size_t)bidx * TLEN * 3;

    // --- stage weight row into registers (64 VGPRs) ---
    const float* wrow;
    float bias = 0.0f;
    if (role == 0)      { wrow = W_hh0 + r * HID; bias = b_ih0[r] + b_hh0[r]; }
    else if (role == 1) { wrow = W_ih1 + r * HID; bias = b_ih1[r] + b_hh1[r]; }
    else                { wrow = W_hh1 + r * HID; }

    float w[HID];
    #pragma unroll
    for (int k4 = 0; k4 < HID / 4; ++k4) {
        float4 v = reinterpret_cast<const float4*>(wrow)[k4];
        w[4*k4+0] = v.x; w[4*k4+1] = v.y; w[4*k4+2] = v.z; w[4*k4+3] = v.w;
    }

    float wi0 = 0.f, wi1 = 0.f, wi2 = 0.f;
    if (role == 0) { wi0 = W_ih0[r*3+0]; wi1 = W_ih0[r*3+1]; wi2 = W_ih0[r*3+2]; }

    // out-projection weights for wave 1
    float wo0 = 0.f, wo1 = 0.f, wo2 = 0.f, bo0 = 0.f, bo1 = 0.f, bo2 = 0.f;
    if (tid >= 64 && tid < 128) {
        int j = tid - 64;
        wo0 = W_out[0*HID + j]; wo1 = W_out[1*HID + j]; wo2 = W_out[2*HID + j];
        bo0 = b_out[0]; bo1 = b_out[1]; bo2 = b_out[2];
    }

    if (tid < HID) { a_lds[tid] = 0.0f; b_lds[tid] = 0.0f; }
    float c_state = 0.0f;   // c0 for tids 0..63, c1 for tids 64..127
    __syncthreads();

    float x0 = 0.f, x1 = 0.f, x2 = 0.f;
    if (role == 0) { x0 = xb[0]; x1 = xb[1]; x2 = xb[2]; }

    for (int t = 0; t <= TLEN; ++t) {
        // ---------- phase A: matvec dots ----------
        float nx0 = 0.f, nx1 = 0.f, nx2 = 0.f;
        if (role == 0 && t + 1 < TLEN) {
            nx0 = xb[3*(t+1)+0]; nx1 = xb[3*(t+1)+1]; nx2 = xb[3*(t+1)+2];
        }
        const float4* h4 = (role == 2) ? reinterpret_cast<const float4*>(b_lds)
                                       : reinterpret_cast<const float4*>(a_lds);
        if (role != 0 || t < TLEN) {
            float a0 = bias, a1 = 0.0f, a2 = 0.0f, a3 = 0.0f;
            if (role == 0) {
                a0 = fmaf(wi0, x0, a0);
                a1 = fmaf(wi1, x1, a1);
                a2 = fmaf(wi2, x2, a2);
            }
            #pragma unroll
            for (int k4 = 0; k4 < HID / 4; ++k4) {
                float4 hv = h4[k4];
                a0 = fmaf(w[4*k4+0], hv.x, a0);
                a1 = fmaf(w[4*k4+1], hv.y, a1);
                a2 = fmaf(w[4*k4+2], hv.z, a2);
                a3 = fmaf(w[4*k4+3], hv.w, a3);
            }
            float d = (a0 + a1) + (a2 + a3);
            if (role == 0)      g0[r] = d;
            else if (role == 1) u1[r] = d;
            else                v1[r] = d;
        }
        x0 = nx0; x1 = nx1; x2 = nx2;
        __syncthreads();

        // ---------- phase B: gate combine ----------
        if (tid < 64) {
            if (t < TLEN) {
                float gi = fsig(g0[tid]);
                float gf = fsig(g0[64 + tid]);
                float gg = ftanh(g0[128 + tid]);
                float go = fsig(g0[192 + tid]);
                c_state = fmaf(gf, c_state, gi * gg);
                a_lds[tid] = go * ftanh(c_state);
            }
        } else if (tid < 128) {
            if (t >= 1) {
                int j = tid - 64;
                float gi = fsig(u1[j]        + v1[j]);
                float gf = fsig(u1[64 + j]   + v1[64 + j]);
                float gg = ftanh(u1[128 + j] + v1[128 + j]);
                float go = fsig(u1[192 + j]  + v1[192 + j]);
                c_state = fmaf(gf, c_state, gi * gg);
                float bnew = go * ftanh(c_state);
                b_lds[j] = bnew;
                // output projection for time t-1: 3 dot-64 via wave reduce
                float p0 = wo0 * bnew, p1 = wo1 * bnew, p2 = wo2 * bnew;
                #pragma unroll
                for (int off = 32; off > 0; off >>= 1) {
                    p0 += __shfl_xor(p0, off);
                    p1 += __shfl_xor(p1, off);
                    p2 += __shfl_xor(p2, off);
                }
                if (j == 0) {
                    float* o = ob + (size_t)(t - 1) * 3;
                    o[0] = p0 + bo0; o[1] = p1 + bo1; o[2] = p2 + bo2;
                }
            }
        }
        __syncthreads();
    }
}

extern "C" void kernel_launch(void* const* d_in, const int* in_sizes, int n_in,
                              void* d_out, int out_size, void* d_ws, size_t ws_size,
                              hipStream_t stream) {
    const float* x     = (const float*)d_in[0];
    const float* W_ih0 = (const float*)d_in[1];
    const float* W_hh0 = (const float*)d_in[2];
    const float* b_ih0 = (const float*)d_in[3];
    const float* b_hh0 = (const float*)d_in[4];
    const float* W_ih1 = (const float*)d_in[5];
    const float* W_hh1 = (const float*)d_in[6];
    const float* b_ih1 = (const float*)d_in[7];
    const float* b_hh1 = (const float*)d_in[8];
    const float* W_out = (const float*)d_in[9];
    const float* b_out = (const float*)d_in[10];
    float* out = (float*)d_out;

    const int B = in_sizes[0] / (TLEN * 3);   // 256
    hipLaunchKernelGGL(lstm_fused, dim3(B), dim3(768), 0, stream,
                       x, W_ih0, W_hh0, b_ih0, b_hh0,
                       W_ih1, W_hh1, b_ih1, b_hh1, W_out, b_out, out);
}

// Round 4
// 2164.936 us; speedup vs baseline: 1.0072x; 1.0072x over previous
//
#include <hip/hip_runtime.h>

#define HID 64
#define TLEN 1024
#define GATES 256  // 4*HID

__device__ __forceinline__ float fast_rcp(float x) { return __builtin_amdgcn_rcpf(x); }

__device__ __forceinline__ float fsig(float x) {
    float e = __expf(-x);
    return fast_rcp(1.0f + e);
}

__device__ __forceinline__ float ftanh(float x) {
    float e = __expf(-2.0f * fabsf(x));
    float t = (1.0f - e) * fast_rcp(1.0f + e);
    return copysignf(t, x);
}

// One workgroup per batch element. 768 threads = 12 waves.
//   tids   0..255 : layer0 gate rows (W_hh0 row r in regs, + W_ih0[r][0..2], fused bias)
//   tids 256..511 : layer1 input rows (W_ih1 row r, fused bias)
//   tids 512..767 : layer1 recurrent rows (W_hh1 row r)
// Software pipeline: phase A of iter t computes layer0 dots for time t AND
// layer1 dots for time t-1 (u1 from a[t-1], v1 from b[t-2]) — all waves busy.
// Phase B: wave0 combines layer0 -> a[t]; wave1 combines layer1 -> b[t-1],
// does the 3-wide output projection (shfl reduce) and writes out[t-1].
//
// __launch_bounds__(768, 1): grid == 256 blocks == #CUs, so only 1 block/CU
// can ever be resident — do NOT let the allocator cap VGPRs for occupancy.
// (768,3) capped at 64 VGPRs and spilled the 64-float weight row to scratch:
// measured 2256 us. Weight row MUST stay register-resident.
__global__ __launch_bounds__(768, 1)
void lstm_fused(const float* __restrict__ x,
                const float* __restrict__ W_ih0, const float* __restrict__ W_hh0,
                const float* __restrict__ b_ih0, const float* __restrict__ b_hh0,
                const float* __restrict__ W_ih1, const float* __restrict__ W_hh1,
                const float* __restrict__ b_ih1, const float* __restrict__ b_hh1,
                const float* __restrict__ W_out, const float* __restrict__ b_out,
                float* __restrict__ out)
{
    __shared__ __align__(16) float a_lds[HID];   // layer0 hidden state
    __shared__ __align__(16) float b_lds[HID];   // layer1 hidden state
    __shared__ __align__(16) float g0[GATES];    // layer0 gate preacts
    __shared__ __align__(16) float u1[GATES];    // W_ih1 @ a
    __shared__ __align__(16) float v1[GATES];    // W_hh1 @ b

    const int tid  = threadIdx.x;
    const int bidx = blockIdx.x;
    const int role = tid >> 8;      // 0,1,2
    const int r    = tid & 255;

    const float* xb = x   + (size_t)bidx * TLEN * 3;
    float*       ob = out + (size_t)bidx * TLEN * 3;

    // --- stage weight row into registers (64 VGPRs) ---
    const float* wrow;
    float bias = 0.0f;
    if (role == 0)      { wrow = W_hh0 + r * HID; bias = b_ih0[r] + b_hh0[r]; }
    else if (role == 1) { wrow = W_ih1 + r * HID; bias = b_ih1[r] + b_hh1[r]; }
    else                { wrow = W_hh1 + r * HID; }

    float w[HID];
    #pragma unroll
    for (int k4 = 0; k4 < HID / 4; ++k4) {
        float4 v = reinterpret_cast<const float4*>(wrow)[k4];
        w[4*k4+0] = v.x; w[4*k4+1] = v.y; w[4*k4+2] = v.z; w[4*k4+3] = v.w;
    }

    float wi0 = 0.f, wi1 = 0.f, wi2 = 0.f;
    if (role == 0) { wi0 = W_ih0[r*3+0]; wi1 = W_ih0[r*3+1]; wi2 = W_ih0[r*3+2]; }

    // out-projection weights for wave 1
    float wo0 = 0.f, wo1 = 0.f, wo2 = 0.f, bo0 = 0.f, bo1 = 0.f, bo2 = 0.f;
    if (tid >= 64 && tid < 128) {
        int j = tid - 64;
        wo0 = W_out[0*HID + j]; wo1 = W_out[1*HID + j]; wo2 = W_out[2*HID + j];
        bo0 = b_out[0]; bo1 = b_out[1]; bo2 = b_out[2];
    }

    if (tid < HID) { a_lds[tid] = 0.0f; b_lds[tid] = 0.0f; }
    float c_state = 0.0f;   // c0 for tids 0..63, c1 for tids 64..127
    __syncthreads();

    float x0 = 0.f, x1 = 0.f, x2 = 0.f;
    if (role == 0) { x0 = xb[0]; x1 = xb[1]; x2 = xb[2]; }

    for (int t = 0; t <= TLEN; ++t) {
        // ---------- phase A: matvec dots ----------
        float nx0 = 0.f, nx1 = 0.f, nx2 = 0.f;
        if (role == 0 && t + 1 < TLEN) {
            nx0 = xb[3*(t+1)+0]; nx1 = xb[3*(t+1)+1]; nx2 = xb[3*(t+1)+2];
        }
        const float4* h4 = (role == 2) ? reinterpret_cast<const float4*>(b_lds)
                                       : reinterpret_cast<const float4*>(a_lds);
        if (role != 0 || t < TLEN) {
            float a0 = bias, a1 = 0.0f, a2 = 0.0f, a3 = 0.0f;
            if (role == 0) {
                a0 = fmaf(wi0, x0, a0);
                a1 = fmaf(wi1, x1, a1);
                a2 = fmaf(wi2, x2, a2);
            }
            #pragma unroll
            for (int k4 = 0; k4 < HID / 4; ++k4) {
                float4 hv = h4[k4];
                a0 = fmaf(w[4*k4+0], hv.x, a0);
                a1 = fmaf(w[4*k4+1], hv.y, a1);
                a2 = fmaf(w[4*k4+2], hv.z, a2);
                a3 = fmaf(w[4*k4+3], hv.w, a3);
            }
            float d = (a0 + a1) + (a2 + a3);
            if (role == 0)      g0[r] = d;
            else if (role == 1) u1[r] = d;
            else                v1[r] = d;
        }
        x0 = nx0; x1 = nx1; x2 = nx2;
        __syncthreads();

        // ---------- phase B: gate combine ----------
        if (tid < 64) {
            if (t < TLEN) {
                float gi = fsig(g0[tid]);
                float gf = fsig(g0[64 + tid]);
                float gg = ftanh(g0[128 + tid]);
                float go = fsig(g0[192 + tid]);
                c_state = fmaf(gf, c_state, gi * gg);
                a_lds[tid] = go * ftanh(c_state);
            }
        } else if (tid < 128) {
            if (t >= 1) {
                int j = tid - 64;
                float gi = fsig(u1[j]        + v1[j]);
                float gf = fsig(u1[64 + j]   + v1[64 + j]);
                float gg = ftanh(u1[128 + j] + v1[128 + j]);
                float go = fsig(u1[192 + j]  + v1[192 + j]);
                c_state = fmaf(gf, c_state, gi * gg);
                float bnew = go * ftanh(c_state);
                b_lds[j] = bnew;
                // output projection for time t-1: 3 dot-64 via wave reduce
                float p0 = wo0 * bnew, p1 = wo1 * bnew, p2 = wo2 * bnew;
                #pragma unroll
                for (int off = 32; off > 0; off >>= 1) {
                    p0 += __shfl_xor(p0, off);
                    p1 += __shfl_xor(p1, off);
                    p2 += __shfl_xor(p2, off);
                }
                if (j == 0) {
                    float* o = ob + (size_t)(t - 1) * 3;
                    o[0] = p0 + bo0; o[1] = p1 + bo1; o[2] = p2 + bo2;
                }
            }
        }
        __syncthreads();
    }
}

extern "C" void kernel_launch(void* const* d_in, const int* in_sizes, int n_in,
                              void* d_out, int out_size, void* d_ws, size_t ws_size,
                              hipStream_t stream) {
    const float* x     = (const float*)d_in[0];
    const float* W_ih0 = (const float*)d_in[1];
    const float* W_hh0 = (const float*)d_in[2];
    const float* b_ih0 = (const float*)d_in[3];
    const float* b_hh0 = (const float*)d_in[4];
    const float* W_ih1 = (const float*)d_in[5];
    const float* W_hh1 = (const float*)d_in[6];
    const float* b_ih1 = (const float*)d_in[7];
    const float* b_hh1 = (const float*)d_in[8];
    const float* W_out = (const float*)d_in[9];
    const float* b_out = (const float*)d_in[10];
    float* out = (float*)d_out;

    const int B = in_sizes[0] / (TLEN * 3);   // 256
    hipLaunchKernelGGL(lstm_fused, dim3(B), dim3(768), 0, stream,
                       x, W_ih0, W_hh0, b_ih0, b_hh0,
                       W_ih1, W_hh1, b_ih1, b_hh1, W_out, b_out, out);
}

// Round 5
// 2153.476 us; speedup vs baseline: 1.0125x; 1.0053x over previous
//
#include <hip/hip_runtime.h>

#define HID 64
#define TLEN 1024
#define GATES 256  // 4*HID

__device__ __forceinline__ float fast_rcp(float x) { return __builtin_amdgcn_rcpf(x); }

__device__ __forceinline__ float fsig(float x) {
    float e = __expf(-x);
    return fast_rcp(1.0f + e);
}

__device__ __forceinline__ float ftanh(float x) {
    float e = __expf(-2.0f * fabsf(x));
    float t = (1.0f - e) * fast_rcp(1.0f + e);
    return copysignf(t, x);
}

// One workgroup per batch element (grid = 256 = #CUs, so exactly 1 block/CU).
// 768 threads = 12 waves = 3 waves/EU.
//   tids   0..255 : layer0 gate rows (W_hh0 row r in regs, + W_ih0[r][0..2], fused bias)
//   tids 256..511 : layer1 input rows (W_ih1 row r, fused bias)
//   tids 512..767 : layer1 recurrent rows (W_hh1 row r)
// Phase A of iter t: layer0 dots for time t AND layer1 dots for time t-1.
// Phase B: wave0 combines layer0 -> a[t]; wave1 combines layer1 -> b[t-1] and
// writes the 3-wide output projection for t-1 via wave reduce.
//
// R3 lesson: __launch_bounds__ 2nd arg (min waves/EU) only RAISES the register
// ceiling; the scheduler still TARGETS 8 waves/EU and demoted w[64] to
// per-step reloads (VGPR_Count=64, 2250us). amdgpu_waves_per_eu(3,3) sets the
// occupancy TARGET to our actual residency (3 waves/EU); the asm pins force
// the weight row to stay materialized in VGPRs.
__global__ __launch_bounds__(768)
__attribute__((amdgpu_waves_per_eu(3, 3)))
void lstm_fused(const float* __restrict__ x,
                const float* __restrict__ W_ih0, const float* __restrict__ W_hh0,
                const float* __restrict__ b_ih0, const float* __restrict__ b_hh0,
                const float* __restrict__ W_ih1, const float* __restrict__ W_hh1,
                const float* __restrict__ b_ih1, const float* __restrict__ b_hh1,
                const float* __restrict__ W_out, const float* __restrict__ b_out,
                float* __restrict__ out)
{
    __shared__ __align__(16) float a_lds[HID];   // layer0 hidden state
    __shared__ __align__(16) float b_lds[HID];   // layer1 hidden state
    __shared__ __align__(16) float g0[GATES];    // layer0 gate preacts
    __shared__ __align__(16) float u1[GATES];    // W_ih1 @ a
    __shared__ __align__(16) float v1[GATES];    // W_hh1 @ b

    const int tid  = threadIdx.x;
    const int bidx = blockIdx.x;
    const int role = tid >> 8;      // 0,1,2
    const int r    = tid & 255;

    const float* xb = x   + (size_t)bidx * TLEN * 3;
    float*       ob = out + (size_t)bidx * TLEN * 3;

    // --- stage weight row into registers (64 VGPRs) ---
    const float* wrow;
    float bias = 0.0f;
    if (role == 0)      { wrow = W_hh0 + r * HID; bias = b_ih0[r] + b_hh0[r]; }
    else if (role == 1) { wrow = W_ih1 + r * HID; bias = b_ih1[r] + b_hh1[r]; }
    else                { wrow = W_hh1 + r * HID; }

    float w[HID];
    #pragma unroll
    for (int k4 = 0; k4 < HID / 4; ++k4) {
        float4 v = reinterpret_cast<const float4*>(wrow)[k4];
        w[4*k4+0] = v.x; w[4*k4+1] = v.y; w[4*k4+2] = v.z; w[4*k4+3] = v.w;
    }
    // Pin the weight row into VGPRs: opaque to the scheduler, cannot be
    // rematerialized/sunk into the loop as per-step reloads.
    #pragma unroll
    for (int k = 0; k < HID; ++k) {
        asm volatile("" : "+v"(w[k]));
    }

    float wi0 = 0.f, wi1 = 0.f, wi2 = 0.f;
    if (role == 0) { wi0 = W_ih0[r*3+0]; wi1 = W_ih0[r*3+1]; wi2 = W_ih0[r*3+2]; }

    // out-projection weights for wave 1
    float wo0 = 0.f, wo1 = 0.f, wo2 = 0.f, bo0 = 0.f, bo1 = 0.f, bo2 = 0.f;
    if (tid >= 64 && tid < 128) {
        int j = tid - 64;
        wo0 = W_out[0*HID + j]; wo1 = W_out[1*HID + j]; wo2 = W_out[2*HID + j];
        bo0 = b_out[0]; bo1 = b_out[1]; bo2 = b_out[2];
    }

    if (tid < HID) { a_lds[tid] = 0.0f; b_lds[tid] = 0.0f; }
    float c_state = 0.0f;   // c0 for tids 0..63, c1 for tids 64..127
    __syncthreads();

    float x0 = 0.f, x1 = 0.f, x2 = 0.f;
    if (role == 0) { x0 = xb[0]; x1 = xb[1]; x2 = xb[2]; }

    for (int t = 0; t <= TLEN; ++t) {
        // ---------- phase A: matvec dots ----------
        float nx0 = 0.f, nx1 = 0.f, nx2 = 0.f;
        if (role == 0 && t + 1 < TLEN) {
            nx0 = xb[3*(t+1)+0]; nx1 = xb[3*(t+1)+1]; nx2 = xb[3*(t+1)+2];
        }
        const float4* h4 = (role == 2) ? reinterpret_cast<const float4*>(b_lds)
                                       : reinterpret_cast<const float4*>(a_lds);
        if (role != 0 || t < TLEN) {
            float a0 = bias, a1 = 0.0f, a2 = 0.0f, a3 = 0.0f;
            if (role == 0) {
                a0 = fmaf(wi0, x0, a0);
                a1 = fmaf(wi1, x1, a1);
                a2 = fmaf(wi2, x2, a2);
            }
            #pragma unroll
            for (int k4 = 0; k4 < HID / 4; ++k4) {
                float4 hv = h4[k4];
                a0 = fmaf(w[4*k4+0], hv.x, a0);
                a1 = fmaf(w[4*k4+1], hv.y, a1);
                a2 = fmaf(w[4*k4+2], hv.z, a2);
                a3 = fmaf(w[4*k4+3], hv.w, a3);
            }
            float d = (a0 + a1) + (a2 + a3);
            if (role == 0)      g0[r] = d;
            else if (role == 1) u1[r] = d;
            else                v1[r] = d;
        }
        x0 = nx0; x1 = nx1; x2 = nx2;
        __syncthreads();

        // ---------- phase B: gate combine ----------
        if (tid < 64) {
            if (t < TLEN) {
                float gi = fsig(g0[tid]);
                float gf = fsig(g0[64 + tid]);
                float gg = ftanh(g0[128 + tid]);
                float go = fsig(g0[192 + tid]);
                c_state = fmaf(gf, c_state, gi * gg);
                a_lds[tid] = go * ftanh(c_state);
            }
        } else if (tid < 128) {
            if (t >= 1) {
                int j = tid - 64;
                float gi = fsig(u1[j]        + v1[j]);
                float gf = fsig(u1[64 + j]   + v1[64 + j]);
                float gg = ftanh(u1[128 + j] + v1[128 + j]);
                float go = fsig(u1[192 + j]  + v1[192 + j]);
                c_state = fmaf(gf, c_state, gi * gg);
                float bnew = go * ftanh(c_state);
                b_lds[j] = bnew;
                // output projection for time t-1: 3 dot-64 via wave reduce
                float p0 = wo0 * bnew, p1 = wo1 * bnew, p2 = wo2 * bnew;
                #pragma unroll
                for (int off = 32; off > 0; off >>= 1) {
                    p0 += __shfl_xor(p0, off);
                    p1 += __shfl_xor(p1, off);
                    p2 += __shfl_xor(p2, off);
                }
                if (j == 0) {
                    float* o = ob + (size_t)(t - 1) * 3;
                    o[0] = p0 + bo0; o[1] = p1 + bo1; o[2] = p2 + bo2;
                }
            }
        }
        __syncthreads();
    }
}

extern "C" void kernel_launch(void* const* d_in, const int* in_sizes, int n_in,
                              void* d_out, int out_size, void* d_ws, size_t ws_size,
                              hipStream_t stream) {
    const float* x     = (const float*)d_in[0];
    const float* W_ih0 = (const float*)d_in[1];
    const float* W_hh0 = (const float*)d_in[2];
    const float* b_ih0 = (const float*)d_in[3];
    const float* b_hh0 = (const float*)d_in[4];
    const float* W_ih1 = (const float*)d_in[5];
    const float* W_hh1 = (const float*)d_in[6];
    const float* b_ih1 = (const float*)d_in[7];
    const float* b_hh1 = (const float*)d_in[8];
    const float* W_out = (const float*)d_in[9];
    const float* b_out = (const float*)d_in[10];
    float* out = (float*)d_out;

    const int B = in_sizes[0] / (TLEN * 3);   // 256
    hipLaunchKernelGGL(lstm_fused, dim3(B), dim3(768), 0, stream,
                       x, W_ih0, W_hh0, b_ih0, b_hh0,
                       W_ih1, W_hh1, b_ih1, b_hh1, W_out, b_out, out);
}